// Round 1
// baseline (202.214 us; speedup 1.0000x reference)
//
#include <hip/hip_runtime.h>
#include <hip/hip_bf16.h>
#include <cstdint>

// Problem constants (fixed by the reference)
#define NB 4            // batch
#define NS 2048         // sequence
#define ND 512          // feature dim
#define NM 2048         // MAX_LEN (clamp M)
#define NV 4097         // table rows = 2M+1
#define NP 3000         // POS_MAX
#define TROW 8192       // HTrev row length (bf16 elements)
#define CCC 5104        // reversal offset (multiple of 8)
#define EVW 4128        // padded K width for Ebf (multiple of 32, >= 4097)
#define RSW 3080        // rs table row stride

typedef __bf16 bf16x8 __attribute__((ext_vector_type(8)));
typedef float f32x4 __attribute__((ext_vector_type(4)));

typedef const unsigned int __attribute__((address_space(1)))* as1_u32p;
typedef unsigned int __attribute__((address_space(3)))* as3_u32p;

__device__ __forceinline__ void gll16(const void* g, void* l) {
  // async global->LDS, 16B per lane; LDS dest = wave-uniform base + lane*16
  __builtin_amdgcn_global_load_lds((as1_u32p)g, (as3_u32p)l, 16, 0, 0);
}

__device__ __forceinline__ unsigned short f2bf(float f) {
  union { __bf16 b; unsigned short u; } cv;
  cv.b = (__bf16)f;
  return cv.u;
}

__device__ __forceinline__ int lbound_dev(const int* a, int n, int key) {
  int lo = 0, hi = n;
  while (lo < hi) { int mid = (lo + hi) >> 1; if (a[mid] < key) lo = mid + 1; else hi = mid; }
  return lo;  // count of elements < key
}

// ---------- k1: per-batch position histogram (LDS atomics) ----------
__global__ void k1_hist(const int* __restrict__ pos, unsigned int* __restrict__ hist) {
  __shared__ unsigned int h[NP];
  int b = blockIdx.x, tid = threadIdx.x;
  for (int i = tid; i < NP; i += 256) h[i] = 0u;
  __syncthreads();
  const int* pb = pos + b * NS;
  for (int i = tid; i < NS; i += 256) atomicAdd(&h[pb[i]], 1u);
  __syncthreads();
  unsigned int* hb = hist + b * NP;
  for (int i = tid; i < NP; i += 256) hb[i] = h[i];
}

// ---------- k1b: rs[b][t] = #{ j : pos_j < t } for t in [0, 3073) ----------
__global__ void k1b_rs(const int* __restrict__ pos, int* __restrict__ rs) {
  int t = blockIdx.x * 256 + threadIdx.x;
  int b = blockIdx.y;
  if (t > 3072) return;
  rs[b * RSW + t] = lbound_dev(pos + b * NS, NS, t);
}

// ---------- k2: HTrev[b][u][t] = bf16(histext[CCC + u - t]), u in [0,16) ----------
__global__ void k2_htrev(const unsigned int* __restrict__ hist, unsigned short* __restrict__ HT) {
  int idx = blockIdx.x * 256 + threadIdx.x;        // 65536 total (= NB*16*TROW/8)
  int b = idx >> 14, rem = idx & 16383;
  int u = rem >> 10, t8 = rem & 1023;
  const unsigned int* hb = hist + b * NP;
  int basep = CCC + u - t8 * 8;
  union { unsigned short us[8]; uint4 v4; } pk;
#pragma unroll
  for (int e = 0; e < 8; ++e) {
    int p = basep - e;
    float f = (p >= 0 && p < NP) ? (float)hb[p] : 0.0f;
    pk.us[e] = f2bf(f);
  }
  *(uint4*)(HT + (size_t)(b * 16 + u) * TROW + t8 * 8) = pk.v4;
}

// ---------- k3: Ebf[d][v] = bf16(emb[v][d]), zeroed at v=0, v=4096, v>=4097 ----------
__global__ void k3_ebf(const float* __restrict__ emb, unsigned short* __restrict__ EB) {
  __shared__ float tile[64][65];
  int v0 = blockIdx.x * 64, d0 = blockIdx.y * 64, tid = threadIdx.x;
  int c = tid & 63, r0 = tid >> 6;
#pragma unroll
  for (int k = 0; k < 16; ++k) {
    int r = k * 4 + r0;
    int v = v0 + r;
    float val = 0.f;
    if (v < NV && v != 0 && v != (NV - 1)) val = emb[(size_t)v * ND + d0 + c];
    tile[r][c] = val;
  }
  __syncthreads();
  int vv0 = (tid & 7) * 8;
#pragma unroll
  for (int k2 = 0; k2 < 2; ++k2) {
    int dd = (tid >> 3) + k2 * 32;
    if (v0 + vv0 + 8 <= EVW) {
      union { unsigned short us[8]; uint4 v4; } pk;
#pragma unroll
      for (int e = 0; e < 8; ++e) pk.us[e] = f2bf(tile[vv0 + e][dd]);
      *(uint4*)(EB + (size_t)(d0 + dd) * EVW + v0 + vv0) = pk.v4;
    }
  }
}

// ---------- k4: Toeplitz GEMM in q-space + fused scatter epilogue ----------
// R[q,d] = sum_v hist[q+M-v] * emb[v,d]  (v in window), then
// out[b,i,d] = x[b,i,d] + (R[pos_i,d] + cge*emb[2M,d] + cle*emb[0,d]) / S
__global__ __launch_bounds__(256, 2)
void k4_gemm(const unsigned short* __restrict__ HT, const unsigned short* __restrict__ EB,
             const int* __restrict__ rs, const float* __restrict__ x,
             const float* __restrict__ emb, float* __restrict__ out) {
  int Q0 = blockIdx.x * 128, d0 = blockIdx.y * 128, b = blockIdx.z;
  int tid = threadIdx.x, w = tid >> 6, lane = tid & 63;
  int wm = w >> 1, wn = w & 1;          // 2x2 wave grid over 128x128 tile
  __shared__ unsigned short As[2][4096]; // 8KB per buf: [chunk mf][u][g][8]
  __shared__ unsigned short Bs[2][4096]; // 8KB per buf: [dloc][32]

  const unsigned short* HTb = HT + (size_t)b * 16 * TROW;
  int u4 = lane >> 2, g4 = lane & 3;    // staging lane decomposition

  int v_lo = (Q0 > 951) ? ((Q0 - 951) & ~31) : 0;
  int v_hi = Q0 + 2176; if (v_hi > EVW) v_hi = EVW;

  f32x4 acc[4][4];
#pragma unroll
  for (int a1 = 0; a1 < 4; ++a1)
#pragma unroll
    for (int a2 = 0; a2 < 4; ++a2) { f32x4 z = {0.f, 0.f, 0.f, 0.f}; acc[a1][a2] = z; }

  const unsigned short* asrc_lane = HTb + u4 * TROW + g4 * 8;

  auto stage = [&](int sbuf, int kk) {
#pragma unroll
    for (int ci = 0; ci < 2; ++ci) {
      int c = w + ci * 4;               // chunk 0..7, wave-uniform
      int t0 = CCC - Q0 - NM - 16 * c + kk;
      gll16(asrc_lane + t0, &As[sbuf][c * 512]);
      const unsigned short* bsrc = EB + (size_t)(d0 + c * 16 + u4) * EVW + kk + g4 * 8;
      gll16(bsrc, &Bs[sbuf][c * 512]);
    }
  };

  stage(0, v_lo);
  __syncthreads();

  int arow = (lane & 15) * 32 + (lane >> 4) * 8;
  int bcol0 = (wn * 64 + (lane & 15)) * 32 + (lane >> 4) * 8;
  int buf = 0;
  for (int kk = v_lo; kk < v_hi; kk += 32) {
    if (kk + 32 < v_hi) stage(buf ^ 1, kk + 32);
    bf16x8 af[4], bfr[4];
#pragma unroll
    for (int mf = 0; mf < 4; ++mf)
      af[mf] = *reinterpret_cast<const bf16x8*>(&As[buf][(wm * 4 + mf) * 512 + arow]);
#pragma unroll
    for (int nf = 0; nf < 4; ++nf)
      bfr[nf] = *reinterpret_cast<const bf16x8*>(&Bs[buf][bcol0 + nf * 512]);
#pragma unroll
    for (int mf = 0; mf < 4; ++mf)
#pragma unroll
      for (int nf = 0; nf < 4; ++nf)
        acc[mf][nf] = __builtin_amdgcn_mfma_f32_16x16x32_bf16(af[mf], bfr[nf], acc[mf][nf], 0, 0, 0);
    __syncthreads();
    buf ^= 1;
  }

  // Epilogue: scatter each q-row to all i with pos_i == q (contiguous via rs)
  const int* rsb = rs + b * RSW;
  const float* xb = x + (size_t)b * NS * ND;
  float* outb = out + (size_t)b * NS * ND;
  int col = lane & 15, rb4 = (lane >> 4) * 4;
#pragma unroll
  for (int nf = 0; nf < 4; ++nf) {
    int dcol = d0 + wn * 64 + nf * 16 + col;
    float e0v = emb[dcol];                          // emb row 0 (fp32, exact)
    float eMv = emb[(size_t)(NV - 1) * ND + dcol];  // emb row 2M
#pragma unroll
    for (int mf = 0; mf < 4; ++mf) {
#pragma unroll
      for (int j = 0; j < 4; ++j) {
        int q = Q0 + wm * 64 + mf * 16 + rb4 + j;
        if (q >= NP) continue;
        int i0 = rsb[q], i1 = rsb[q + 1];
        if (i0 == i1) continue;
        int cge = (q >= NM) ? rsb[q - NM + 1] : 0;          // #{pos_j <= q-M}
        int cle = (q + NM < NP) ? (NS - rsb[q + NM]) : 0;   // #{pos_j >= q+M}
        float val = (acc[mf][nf][j] + (float)cge * eMv + (float)cle * e0v) * (1.0f / (float)NS);
        for (int i = i0; i < i1; ++i)
          outb[(size_t)i * ND + dcol] = xb[(size_t)i * ND + dcol] + val;
      }
    }
  }
}

extern "C" void kernel_launch(void* const* d_in, const int* in_sizes, int n_in,
                              void* d_out, int out_size, void* d_ws, size_t ws_size,
                              hipStream_t stream) {
  const float* x = (const float*)d_in[0];
  const float* emb = (const float*)d_in[1];
  const int* pos = (const int*)d_in[2];
  float* out = (float*)d_out;

  char* ws = (char*)d_ws;
  unsigned short* HT = (unsigned short*)(ws);                 // 4*16*8192*2   = 1,048,576 B
  unsigned short* EB = (unsigned short*)(ws + 1048576);       // 512*4128*2    = 4,227,072 B
  unsigned int* hist = (unsigned int*)(ws + 5275648);         // 4*3000*4      = 48,000 B
  int* rs = (int*)(ws + 5323648);                             // 4*3080*4      = 49,280 B
  // total ws use ~5.4 MB

  hipLaunchKernelGGL(k1_hist, dim3(NB), dim3(256), 0, stream, pos, hist);
  hipLaunchKernelGGL(k1b_rs, dim3(13, NB), dim3(256), 0, stream, pos, rs);
  hipLaunchKernelGGL(k2_htrev, dim3(256), dim3(256), 0, stream, hist, HT);
  hipLaunchKernelGGL(k3_ebf, dim3(65, 8), dim3(256), 0, stream, emb, EB);
  hipLaunchKernelGGL(k4_gemm, dim3(24, 4, NB), dim3(256), 0, stream, HT, EB, rs, x, emb, out);
}

// Round 3
// 188.237 us; speedup vs baseline: 1.0743x; 1.0743x over previous
//
#include <hip/hip_runtime.h>
#include <hip/hip_bf16.h>
#include <cstdint>

// Problem constants (fixed by the reference)
#define NB 4            // batch
#define NS 2048         // sequence
#define ND 512          // feature dim
#define NM 2048         // MAX_LEN (clamp M)
#define NV 4097         // table rows = 2M+1
#define NP 3000         // POS_MAX
#define TROW 8192       // HTrev row length (bf16 elements)
#define CCC 5104        // reversal offset (multiple of 8)
#define EVW 4128        // padded K width for Ebf (multiple of 32, >= 4097)
#define RSW 3080        // rs table row stride

typedef __bf16 bf16x8 __attribute__((ext_vector_type(8)));
typedef float f32x4 __attribute__((ext_vector_type(4)));

typedef const unsigned int __attribute__((address_space(1)))* as1_u32p;
typedef unsigned int __attribute__((address_space(3)))* as3_u32p;

__device__ __forceinline__ void gll16(const void* g, void* l) {
  // async global->LDS, 16B per lane; LDS dest = wave-uniform base + lane*16
  __builtin_amdgcn_global_load_lds((as1_u32p)g, (as3_u32p)l, 16, 0, 0);
}

__device__ __forceinline__ unsigned short f2bf(float f) {
  union { __bf16 b; unsigned short u; } cv;
  cv.b = (__bf16)f;
  return cv.u;
}

__device__ __forceinline__ int lbound_dev(const int* a, int n, int key) {
  int lo = 0, hi = n;
  while (lo < hi) { int mid = (lo + hi) >> 1; if (a[mid] < key) lo = mid + 1; else hi = mid; }
  return lo;  // count of elements < key
}

// ---------- k1: per-batch histogram (LDS atomics) + rs lower-bound table ----------
__global__ void k1_hist(const int* __restrict__ pos, unsigned int* __restrict__ hist,
                        int* __restrict__ rs) {
  __shared__ unsigned int h[NP];
  int b = blockIdx.x, tid = threadIdx.x;
  for (int i = tid; i < NP; i += 256) h[i] = 0u;
  __syncthreads();
  const int* pb = pos + b * NS;
  for (int i = tid; i < NS; i += 256) atomicAdd(&h[pb[i]], 1u);
  __syncthreads();
  unsigned int* hb = hist + b * NP;
  for (int i = tid; i < NP; i += 256) hb[i] = h[i];
  for (int t = tid; t <= 3072; t += 256) rs[b * RSW + t] = lbound_dev(pb, NS, t);
}

// ---------- k2: HTrev[b][u][t] = bf16(histext[CCC + u - t]), u in [0,16) ----------
__global__ void k2_htrev(const unsigned int* __restrict__ hist, unsigned short* __restrict__ HT) {
  int idx = blockIdx.x * 256 + threadIdx.x;        // 65536 total (= NB*16*TROW/8)
  int b = idx >> 14, rem = idx & 16383;
  int u = rem >> 10, t8 = rem & 1023;
  const unsigned int* hb = hist + b * NP;
  int basep = CCC + u - t8 * 8;
  union { unsigned short us[8]; uint4 v4; } pk;
#pragma unroll
  for (int e = 0; e < 8; ++e) {
    int p = basep - e;
    float f = (p >= 0 && p < NP) ? (float)hb[p] : 0.0f;
    pk.us[e] = f2bf(f);
  }
  *(uint4*)(HT + (size_t)(b * 16 + u) * TROW + t8 * 8) = pk.v4;
}

// ---------- k3: Ebf[d][v] = bf16(emb[v][d]), zeroed at v=0, v=4096, v>=4097 ----------
__global__ void k3_ebf(const float* __restrict__ emb, unsigned short* __restrict__ EB) {
  __shared__ float tile[64][65];
  int v0 = blockIdx.x * 64, d0 = blockIdx.y * 64, tid = threadIdx.x;
  int c = tid & 63, r0 = tid >> 6;
#pragma unroll
  for (int k = 0; k < 16; ++k) {
    int r = k * 4 + r0;
    int v = v0 + r;
    float val = 0.f;
    if (v < NV && v != 0 && v != (NV - 1)) val = emb[(size_t)v * ND + d0 + c];
    tile[r][c] = val;
  }
  __syncthreads();
  int vv0 = (tid & 7) * 8;
#pragma unroll
  for (int k2 = 0; k2 < 2; ++k2) {
    int dd = (tid >> 3) + k2 * 32;
    if (v0 + vv0 + 8 <= EVW) {
      union { unsigned short us[8]; uint4 v4; } pk;
#pragma unroll
      for (int e = 0; e < 8; ++e) pk.us[e] = f2bf(tile[vv0 + e][dd]);
      *(uint4*)(EB + (size_t)(d0 + dd) * EVW + v0 + vv0) = pk.v4;
    }
  }
}

// ---------- k4: Toeplitz GEMM in q-space + fused scatter epilogue ----------
// Tile: 64 q x 128 d, K-step 32. 4 waves in 2x2 grid, each wave 32q x 64d (acc[2][4]).
// LDS chunk layout [g][u] -> staging lane l: u=l&15, g=l>>4; read offset
// (lane>>4)*128 + (lane&15)*8 elements = fully sequential 1KB per wave read
// (conflict-free ds_read_b128).
__global__ __launch_bounds__(256, 3)
void k4_gemm(const unsigned short* __restrict__ HT, const unsigned short* __restrict__ EB,
             const int* __restrict__ rs, const float* __restrict__ x,
             const float* __restrict__ emb, float* __restrict__ out) {
  int Q0 = blockIdx.x * 64, d0 = blockIdx.y * 128, b = blockIdx.z;
  int tid = threadIdx.x, w = tid >> 6, lane = tid & 63;
  int wm = w >> 1, wn = w & 1;          // 2x2 wave grid over 64x128 tile
  __shared__ unsigned short As[2][2048]; // 4KB per buf: 4 chunks of [g][u][8]
  __shared__ unsigned short Bs[2][4096]; // 8KB per buf: 8 chunks of [g][dloc][8]

  const unsigned short* HTb = HT + (size_t)b * 16 * TROW;
  int ul = lane & 15, gl = lane >> 4;   // staging lane decomposition ([g][u] layout)

  int v_lo = (Q0 > 951) ? ((Q0 - 951) & ~31) : 0;
  int v_hi = Q0 + 2112; if (v_hi > EVW) v_hi = EVW;

  f32x4 acc[2][4];
#pragma unroll
  for (int a1 = 0; a1 < 2; ++a1)
#pragma unroll
    for (int a2 = 0; a2 < 4; ++a2) { f32x4 z = {0.f, 0.f, 0.f, 0.f}; acc[a1][a2] = z; }

  const unsigned short* asrc_lane = HTb + ul * TROW + gl * 8;

  auto stage = [&](int sbuf, int kk) {
    // A chunk c = w (covers q-block w*16..w*16+16)
    int t0 = CCC - Q0 - NM - 16 * w + kk;
    gll16(asrc_lane + t0, &As[sbuf][w * 512]);
    // B chunks w and w+4
#pragma unroll
    for (int ci = 0; ci < 2; ++ci) {
      int c = w + ci * 4;
      const unsigned short* bsrc = EB + (size_t)(d0 + c * 16 + ul) * EVW + kk + gl * 8;
      gll16(bsrc, &Bs[sbuf][c * 512]);
    }
  };

  stage(0, v_lo);
  __syncthreads();

  int aoff = (lane >> 4) * 128 + (lane & 15) * 8;  // shared read offset within a chunk
  int buf = 0;
  for (int kk = v_lo; kk < v_hi; kk += 32) {
    if (kk + 32 < v_hi) stage(buf ^ 1, kk + 32);
    bf16x8 af[2], bfr[4];
#pragma unroll
    for (int mf = 0; mf < 2; ++mf)
      af[mf] = *reinterpret_cast<const bf16x8*>(&As[buf][(wm * 2 + mf) * 512 + aoff]);
#pragma unroll
    for (int nf = 0; nf < 4; ++nf)
      bfr[nf] = *reinterpret_cast<const bf16x8*>(&Bs[buf][(wn * 4 + nf) * 512 + aoff]);
#pragma unroll
    for (int mf = 0; mf < 2; ++mf)
#pragma unroll
      for (int nf = 0; nf < 4; ++nf)
        acc[mf][nf] = __builtin_amdgcn_mfma_f32_16x16x32_bf16(af[mf], bfr[nf], acc[mf][nf], 0, 0, 0);
    __syncthreads();
    buf ^= 1;
  }

  // Epilogue: scatter each q-row to all i with pos_i == q (contiguous via rs)
  const int* rsb = rs + b * RSW;
  const float* xb = x + (size_t)b * NS * ND;
  float* outb = out + (size_t)b * NS * ND;
  int col = lane & 15, rb4 = (lane >> 4) * 4;
#pragma unroll
  for (int nf = 0; nf < 4; ++nf) {
    int dcol = d0 + wn * 64 + nf * 16 + col;
    float e0v = emb[dcol];                          // emb row 0 (fp32, exact)
    float eMv = emb[(size_t)(NV - 1) * ND + dcol];  // emb row 2M
#pragma unroll
    for (int mf = 0; mf < 2; ++mf) {
#pragma unroll
      for (int j = 0; j < 4; ++j) {
        int q = Q0 + wm * 32 + mf * 16 + rb4 + j;
        if (q >= NP) continue;
        int i0 = rsb[q], i1 = rsb[q + 1];
        if (i0 == i1) continue;
        int cge = (q >= NM) ? rsb[q - NM + 1] : 0;          // #{pos_j <= q-M}
        int cle = (q + NM < NP) ? (NS - rsb[q + NM]) : 0;   // #{pos_j >= q+M}
        float val = (acc[mf][nf][j] + (float)cge * eMv + (float)cle * e0v) * (1.0f / (float)NS);
        for (int i = i0; i < i1; ++i)
          outb[(size_t)i * ND + dcol] = xb[(size_t)i * ND + dcol] + val;
      }
    }
  }
}

extern "C" void kernel_launch(void* const* d_in, const int* in_sizes, int n_in,
                              void* d_out, int out_size, void* d_ws, size_t ws_size,
                              hipStream_t stream) {
  const float* x = (const float*)d_in[0];
  const float* emb = (const float*)d_in[1];
  const int* pos = (const int*)d_in[2];
  float* out = (float*)d_out;

  char* ws = (char*)d_ws;
  unsigned short* HT = (unsigned short*)(ws);                 // 4*16*8192*2   = 1,048,576 B
  unsigned short* EB = (unsigned short*)(ws + 1048576);       // 512*4128*2    = 4,227,072 B
  unsigned int* hist = (unsigned int*)(ws + 5275648);         // 4*3000*4      = 48,000 B
  int* rs = (int*)(ws + 5323648);                             // 4*3080*4      = 49,280 B
  // total ws use ~5.4 MB

  hipLaunchKernelGGL(k1_hist, dim3(NB), dim3(256), 0, stream, pos, hist, rs);
  hipLaunchKernelGGL(k2_htrev, dim3(256), dim3(256), 0, stream, hist, HT);
  hipLaunchKernelGGL(k3_ebf, dim3(65, 8), dim3(256), 0, stream, emb, EB);
  hipLaunchKernelGGL(k4_gemm, dim3(47, 4, NB), dim3(256), 0, stream, HT, EB, rs, x, emb, out);
}

// Round 6
// 178.668 us; speedup vs baseline: 1.1318x; 1.0536x over previous
//
#include <hip/hip_runtime.h>
#include <hip/hip_bf16.h>
#include <cstdint>

// Problem constants (fixed by the reference)
#define NB 4            // batch
#define NS 2048         // sequence
#define ND 512          // feature dim
#define NM 2048         // MAX_LEN (clamp M)
#define NV 4097         // table rows = 2M+1
#define NP 3000         // POS_MAX
#define TROW 8192       // HTrev row length (bf16 elements)
#define CCC 5104        // reversal offset (multiple of 8)
#define EVW 4128        // padded K width for Ebf (multiple of 32, >= 4097)
#define RSW 3080        // rs table row stride

typedef __bf16 bf16x8 __attribute__((ext_vector_type(8)));
typedef float f32x4 __attribute__((ext_vector_type(4)));

typedef const unsigned int __attribute__((address_space(1)))* as1_u32p;
typedef unsigned int __attribute__((address_space(3)))* as3_u32p;

__device__ __forceinline__ void gll16(const void* g, void* l) {
  // async global->LDS, 16B per lane; LDS dest = wave-uniform base + lane*16
  __builtin_amdgcn_global_load_lds((as1_u32p)g, (as3_u32p)l, 16, 0, 0);
}

__device__ __forceinline__ unsigned short f2bf(float f) {
  union { __bf16 b; unsigned short u; } cv;
  cv.b = (__bf16)f;
  return cv.u;
}

__device__ __forceinline__ int lbound_dev(const int* a, int n, int key) {
  int lo = 0, hi = n;
  while (lo < hi) { int mid = (lo + hi) >> 1; if (a[mid] < key) lo = mid + 1; else hi = mid; }
  return lo;  // count of elements < key
}

// ---------- k1: per-batch histogram (LDS atomics) ----------
__global__ void k1_hist(const int* __restrict__ pos, unsigned int* __restrict__ hist) {
  __shared__ unsigned int h[NP];
  int b = blockIdx.x, tid = threadIdx.x;
  for (int i = tid; i < NP; i += 256) h[i] = 0u;
  __syncthreads();
  const int* pb = pos + b * NS;
  for (int i = tid; i < NS; i += 256) atomicAdd(&h[pb[i]], 1u);
  __syncthreads();
  unsigned int* hb = hist + b * NP;
  for (int i = tid; i < NP; i += 256) hb[i] = h[i];
}

// ---------- k1b: rs[b][t] = #{ j : pos_j < t } (wide grid, latency-parallel) ----------
__global__ void k1b_rs(const int* __restrict__ pos, int* __restrict__ rs) {
  int t = blockIdx.x * 256 + threadIdx.x;
  int b = blockIdx.y;
  if (t > 3072) return;
  rs[b * RSW + t] = lbound_dev(pos + b * NS, NS, t);
}

// ---------- k2: HTrev[b][u][t] = bf16(histext[CCC + u - t]), u in [0,16) ----------
__global__ void k2_htrev(const unsigned int* __restrict__ hist, unsigned short* __restrict__ HT) {
  int idx = blockIdx.x * 256 + threadIdx.x;        // 65536 total (= NB*16*TROW/8)
  int b = idx >> 14, rem = idx & 16383;
  int u = rem >> 10, t8 = rem & 1023;
  const unsigned int* hb = hist + b * NP;
  int basep = CCC + u - t8 * 8;
  union { unsigned short us[8]; uint4 v4; } pk;
#pragma unroll
  for (int e = 0; e < 8; ++e) {
    int p = basep - e;
    float f = (p >= 0 && p < NP) ? (float)hb[p] : 0.0f;
    pk.us[e] = f2bf(f);
  }
  *(uint4*)(HT + (size_t)(b * 16 + u) * TROW + t8 * 8) = pk.v4;
}

// ---------- k3: Ebf[d][v] = bf16(emb[v][d]), zeroed at v=0, v=4096, v>=4097 ----------
__global__ void k3_ebf(const float* __restrict__ emb, unsigned short* __restrict__ EB) {
  __shared__ float tile[64][65];
  int v0 = blockIdx.x * 64, d0 = blockIdx.y * 64, tid = threadIdx.x;
  int c = tid & 63, r0 = tid >> 6;
#pragma unroll
  for (int k = 0; k < 16; ++k) {
    int r = k * 4 + r0;
    int v = v0 + r;
    float val = 0.f;
    if (v < NV && v != 0 && v != (NV - 1)) val = emb[(size_t)v * ND + d0 + c];
    tile[r][c] = val;
  }
  __syncthreads();
  int vv0 = (tid & 7) * 8;
#pragma unroll
  for (int k2 = 0; k2 < 2; ++k2) {
    int dd = (tid >> 3) + k2 * 32;
    if (v0 + vv0 + 8 <= EVW) {
      union { unsigned short us[8]; uint4 v4; } pk;
#pragma unroll
      for (int e = 0; e < 8; ++e) pk.us[e] = f2bf(tile[vv0 + e][dd]);
      *(uint4*)(EB + (size_t)(d0 + dd) * EVW + v0 + vv0) = pk.v4;
    }
  }
}

// ---------- k4: Toeplitz GEMM in q-space, depth-2 pipelined (counted vmcnt),
//             fused scatter epilogue ----------
// Tile: 64 q x 128 d, K-step 32. 4 waves in 2x2 grid, each wave 32q x 64d (acc[2][4]).
// NBUF=3 LDS buffers; prologue stages t=0,1; loop: waitcnt vmcnt(3) (tile t done,
// t+1 in flight) + lgkmcnt(0) (my ds_reads drained) -> raw s_barrier -> stage t+2.
// Buffers {t,t+1,t+2} mod 3 are distinct; stage into buf t%3 at iter t+1 only
// happens after the barrier all iter-t readers passed. LDS chunk layout [g][u]
// keeps every ds_read_b128 fully sequential (conflict-free, verified r3: 0 conflicts).
__global__ __launch_bounds__(256, 4)
void k4_gemm(const unsigned short* __restrict__ HT, const unsigned short* __restrict__ EB,
             const int* __restrict__ rs, const float* __restrict__ x,
             const float* __restrict__ emb, float* __restrict__ out) {
  int Q0 = blockIdx.x * 64, d0 = blockIdx.y * 128, b = blockIdx.z;
  int tid = threadIdx.x, w = tid >> 6, lane = tid & 63;
  int wm = w >> 1, wn = w & 1;           // 2x2 wave grid over 64x128 tile
  __shared__ unsigned short As[3][2048]; // 4KB per buf: 4 chunks of [g][u][8]
  __shared__ unsigned short Bs[3][4096]; // 8KB per buf: 8 chunks of [g][dloc][8]

  const unsigned short* HTb = HT + (size_t)b * 16 * TROW;
  int ul = lane & 15, gl = lane >> 4;    // staging lane decomposition ([g][u] layout)

  int v_lo = (Q0 > 951) ? ((Q0 - 951) & ~31) : 0;
  int v_hi = Q0 + 2112; if (v_hi > EVW) v_hi = EVW;
  int nt = (v_hi - v_lo) >> 5;           // >= 66 always (window is a multiple of 32)

  f32x4 acc[2][4];
#pragma unroll
  for (int a1 = 0; a1 < 2; ++a1)
#pragma unroll
    for (int a2 = 0; a2 < 4; ++a2) { f32x4 z = {0.f, 0.f, 0.f, 0.f}; acc[a1][a2] = z; }

  const unsigned short* asrc_lane = HTb + ul * TROW + gl * 8;

  auto stage = [&](int sbuf, int t) {
    int kk = v_lo + t * 32;
    // A chunk c = w (covers q-block w*16..w*16+16)
    int t0 = CCC - Q0 - NM - 16 * w + kk;
    gll16(asrc_lane + t0, &As[sbuf][w * 512]);
    // B chunks w and w+4
#pragma unroll
    for (int ci = 0; ci < 2; ++ci) {
      int c = w + ci * 4;
      const unsigned short* bsrc = EB + (size_t)(d0 + c * 16 + ul) * EVW + kk + gl * 8;
      gll16(bsrc, &Bs[sbuf][c * 512]);
    }
  };

  stage(0, 0);
  stage(1, 1);                           // 6 loads/wave in flight

  int aoff = (lane >> 4) * 128 + (lane & 15) * 8;  // read offset within a chunk
  int s0 = 0, s1 = 1, s2 = 2;            // bufs holding tiles t, t+1, t+2
  for (int t = 0; t < nt; ++t) {
    // Drain tile t's loads (3 of 6 outstanding) and my ds_reads, then barrier.
    if (t + 1 < nt) asm volatile("s_waitcnt vmcnt(3) lgkmcnt(0)" ::: "memory");
    else            asm volatile("s_waitcnt vmcnt(0) lgkmcnt(0)" ::: "memory");
    __builtin_amdgcn_s_barrier();
    if (t + 2 < nt) stage(s2, t + 2);

    bf16x8 af[2], bfr[4];
#pragma unroll
    for (int mf = 0; mf < 2; ++mf)
      af[mf] = *reinterpret_cast<const bf16x8*>(&As[s0][(wm * 2 + mf) * 512 + aoff]);
#pragma unroll
    for (int nf = 0; nf < 4; ++nf)
      bfr[nf] = *reinterpret_cast<const bf16x8*>(&Bs[s0][(wn * 4 + nf) * 512 + aoff]);
    __builtin_amdgcn_s_setprio(1);
#pragma unroll
    for (int mf = 0; mf < 2; ++mf)
#pragma unroll
      for (int nf = 0; nf < 4; ++nf)
        acc[mf][nf] = __builtin_amdgcn_mfma_f32_16x16x32_bf16(af[mf], bfr[nf], acc[mf][nf], 0, 0, 0);
    __builtin_amdgcn_s_setprio(0);
    int tmp = s0; s0 = s1; s1 = s2; s2 = tmp;
  }

  // Epilogue: scatter each q-row to all i with pos_i == q (contiguous via rs)
  const int* rsb = rs + b * RSW;
  const float* xb = x + (size_t)b * NS * ND;
  float* outb = out + (size_t)b * NS * ND;
  int col = lane & 15, rb4 = (lane >> 4) * 4;
#pragma unroll
  for (int nf = 0; nf < 4; ++nf) {
    int dcol = d0 + wn * 64 + nf * 16 + col;
    float e0v = emb[dcol];                          // emb row 0 (fp32, exact)
    float eMv = emb[(size_t)(NV - 1) * ND + dcol];  // emb row 2M
#pragma unroll
    for (int mf = 0; mf < 2; ++mf) {
#pragma unroll
      for (int j = 0; j < 4; ++j) {
        int q = Q0 + wm * 32 + mf * 16 + rb4 + j;
        if (q >= NP) continue;
        int i0 = rsb[q], i1 = rsb[q + 1];
        if (i0 == i1) continue;
        int cge = (q >= NM) ? rsb[q - NM + 1] : 0;          // #{pos_j <= q-M}
        int cle = (q + NM < NP) ? (NS - rsb[q + NM]) : 0;   // #{pos_j >= q+M}
        float val = (acc[mf][nf][j] + (float)cge * eMv + (float)cle * e0v) * (1.0f / (float)NS);
        for (int i = i0; i < i1; ++i)
          outb[(size_t)i * ND + dcol] = xb[(size_t)i * ND + dcol] + val;
      }
    }
  }
}

extern "C" void kernel_launch(void* const* d_in, const int* in_sizes, int n_in,
                              void* d_out, int out_size, void* d_ws, size_t ws_size,
                              hipStream_t stream) {
  const float* x = (const float*)d_in[0];
  const float* emb = (const float*)d_in[1];
  const int* pos = (const int*)d_in[2];
  float* out = (float*)d_out;

  char* ws = (char*)d_ws;
  unsigned short* HT = (unsigned short*)(ws);                 // 4*16*8192*2   = 1,048,576 B
  unsigned short* EB = (unsigned short*)(ws + 1048576);       // 512*4128*2    = 4,227,072 B
  unsigned int* hist = (unsigned int*)(ws + 5275648);         // 4*3000*4      = 48,000 B
  int* rs = (int*)(ws + 5323648);                             // 4*3080*4      = 49,280 B
  // total ws use ~5.4 MB

  hipLaunchKernelGGL(k1_hist, dim3(NB), dim3(256), 0, stream, pos, hist);
  hipLaunchKernelGGL(k1b_rs, dim3(13, NB), dim3(256), 0, stream, pos, rs);
  hipLaunchKernelGGL(k2_htrev, dim3(256), dim3(256), 0, stream, hist, HT);
  hipLaunchKernelGGL(k3_ebf, dim3(65, 8), dim3(256), 0, stream, emb, EB);
  hipLaunchKernelGGL(k4_gemm, dim3(47, 4, NB), dim3(256), 0, stream, HT, EB, rs, x, emb, out);
}